// Round 3
// baseline (169.551 us; speedup 1.0000x reference)
//
#include <hip/hip_runtime.h>
#include <math.h>
#include <limits.h>

#define T_LEN 6000
#define B_ROWS 4096
#define PICK_WIN 20
#define BETA 25.0f

// ---------------------------------------------------------------------------
// Fully fused: per-row L1 + argmax(|target|) + windowed soft-argmax pick,
// plus last-block-done final reduce (no second kernel).
// One block per row, 256 threads; 1500 float4/row -> threads 0..219 own 6,
// the rest own 5. All loads issued before any consume (sched_barrier pin).
// ---------------------------------------------------------------------------
__global__ __launch_bounds__(256) void fused_loss(const float* __restrict__ pred,
                                                  const float* __restrict__ target,
                                                  float* __restrict__ row_l1,
                                                  float* __restrict__ row_pick,
                                                  unsigned int* __restrict__ counter,
                                                  float* __restrict__ out) {
    const int row  = blockIdx.x;
    const int tid  = threadIdx.x;
    const int wave = tid >> 6;
    const int lane = tid & 63;

    const float4* __restrict__ p4 = (const float4*)(pred + (size_t)row * T_LEN);
    const float4* __restrict__ t4 = (const float4*)(target + (size_t)row * T_LEN);

    float4 p[6], t[6];
    const bool has6 = (tid < (T_LEN / 4 - 5 * 256));   // tid < 220
    #pragma unroll
    for (int k = 0; k < 5; ++k) {
        p[k] = p4[tid + k * 256];
        t[k] = t4[tid + k * 256];
    }
    if (has6) { p[5] = p4[tid + 5 * 256]; t[5] = t4[tid + 5 * 256]; }

    // Pin: no consume may be hoisted above, no load sunk below -> 12 loads in
    // flight per thread (the round-2 build pipelined them, VGPR=36, ~2.7TB/s).
    __builtin_amdgcn_sched_barrier(0);

    float sum0 = 0.0f, sum1 = 0.0f;
    float bestv = -1.0f;            // |t| >= 0, always beaten
    int   besti = INT_MAX;

    // Indices strictly increase within a thread -> '>' keeps first occurrence.
    #pragma unroll
    for (int k = 0; k < 6; ++k) {
        if (k == 5 && !has6) break;
        const int base = (tid + k * 256) * 4;
        const float4 pp = p[k], tt = t[k];
        sum0 += fabsf(pp.x - tt.x) + fabsf(pp.y - tt.y);
        sum1 += fabsf(pp.z - tt.z) + fabsf(pp.w - tt.w);
        float a;
        a = fabsf(tt.x); if (a > bestv) { bestv = a; besti = base;     }
        a = fabsf(tt.y); if (a > bestv) { bestv = a; besti = base + 1; }
        a = fabsf(tt.z); if (a > bestv) { bestv = a; besti = base + 2; }
        a = fabsf(tt.w); if (a > bestv) { bestv = a; besti = base + 3; }
    }
    float sum = sum0 + sum1;

    // ---- wave-level reduce (no LDS, no barrier): sum + argmax w/ tie->min idx
    #pragma unroll
    for (int o = 32; o > 0; o >>= 1) {
        sum += __shfl_xor(sum, o);
        const float ov = __shfl_xor(bestv, o);
        const int   oi = __shfl_xor(besti, o);
        if (ov > bestv || (ov == bestv && oi < besti)) { bestv = ov; besti = oi; }
    }

    __shared__ float s_sum[4];
    __shared__ float s_val[4];
    __shared__ int   s_idx[4];
    if (lane == 0) { s_sum[wave] = sum; s_val[wave] = bestv; s_idx[wave] = besti; }
    __syncthreads();

    // ---- wave 0: combine 4 partials, then the <=40-wide soft-argmax pick
    if (tid < 64) {
        float bs = 0.0f, bv = -1.0f;
        int   bi = INT_MAX;
        #pragma unroll
        for (int w = 0; w < 4; ++w) {
            bs += s_sum[w];
            if (s_val[w] > bv || (s_val[w] == bv && s_idx[w] < bi)) {
                bv = s_val[w]; bi = s_idx[w];
            }
        }

        const int c   = bi;
        const int s   = max(0, c - PICK_WIN);
        const int e   = min(T_LEN, c + PICK_WIN);
        const int len = e - s;

        float ap = -INFINITY, at = -INFINITY;
        const float posf = (float)(s + tid);
        if (tid < len) {
            const size_t idx = (size_t)row * T_LEN + s + tid;
            ap = BETA * fabsf(pred[idx]);     // L1/L2-hot: just streamed
            at = BETA * fabsf(target[idx]);
        }

        float mp = ap, mt = at;
        #pragma unroll
        for (int o = 32; o > 0; o >>= 1) {
            mp = fmaxf(mp, __shfl_xor(mp, o));
            mt = fmaxf(mt, __shfl_xor(mt, o));
        }

        float wp = 0.0f, wt = 0.0f, wpp = 0.0f, wtp = 0.0f;
        if (tid < len) {
            wp  = expf(ap - mp);
            wt  = expf(at - mt);
            wpp = wp * posf;
            wtp = wt * posf;
        }
        #pragma unroll
        for (int o = 32; o > 0; o >>= 1) {
            wp  += __shfl_xor(wp,  o);
            wt  += __shfl_xor(wt,  o);
            wpp += __shfl_xor(wpp, o);
            wtp += __shfl_xor(wtp, o);
        }

        if (tid == 0) {
            row_l1[row]   = bs;
            row_pick[row] = fabsf(wpp / wp - wtp / wt);
        }
    }

    // ---- last-block-done final reduce (replaces the finalize kernel)
    __syncthreads();
    __shared__ unsigned s_done;
    if (tid == 0) {
        __threadfence();                       // release row_l1/row_pick
        s_done = atomicAdd(counter, 1u);       // device-scope by default (m20)
    }
    __syncthreads();

    if (s_done == (unsigned)(B_ROWS - 1)) {
        __threadfence();                       // acquire (invalidates vL1)
        float a = 0.0f, b = 0.0f;
        for (int i = tid; i < B_ROWS; i += 256) {
            a += row_l1[i];
            b += row_pick[i];
        }
        #pragma unroll
        for (int o = 32; o > 0; o >>= 1) {
            a += __shfl_xor(a, o);
            b += __shfl_xor(b, o);
        }
        __shared__ float f1[4], f2[4];
        if (lane == 0) { f1[wave] = a; f2[wave] = b; }
        __syncthreads();
        if (tid == 0) {
            const float ta = f1[0] + f1[1] + f1[2] + f1[3];
            const float tb = f2[0] + f2[1] + f2[2] + f2[3];
            const float loss = ta / (float)((long long)B_ROWS * (long long)T_LEN);
            const float pick = (tb / (float)B_ROWS) / (float)T_LEN;
            out[0] = loss + 0.1f * pick;
        }
    }
}

extern "C" void kernel_launch(void* const* d_in, const int* in_sizes, int n_in,
                              void* d_out, int out_size, void* d_ws, size_t ws_size,
                              hipStream_t stream) {
    const float* pred   = (const float*)d_in[0];
    const float* target = (const float*)d_in[1];
    float* out = (float*)d_out;

    // workspace: [row_l1: 4096 f32][row_pick: 4096 f32][counter: 1 u32]
    float*    row_l1   = (float*)d_ws;
    float*    row_pick = row_l1 + B_ROWS;
    unsigned* counter  = (unsigned*)(row_pick + B_ROWS);

    hipMemsetAsync(counter, 0, sizeof(unsigned), stream);  // graph memset node
    fused_loss<<<B_ROWS, 256, 0, stream>>>(pred, target, row_l1, row_pick,
                                           counter, out);
}

// Round 4
// 167.195 us; speedup vs baseline: 1.0141x; 1.0141x over previous
//
#include <hip/hip_runtime.h>
#include <math.h>
#include <limits.h>
#include <stdint.h>

#define T_LEN 6000
#define B_ROWS 4096
#define PICK_WIN 20
#define BETA 25.0f
#define SCALE_L1 2097152.0f      // 2^21  (row L1 sums ~7e3 -> <2^34 scaled, f32-exact to ~4e-4)
#define SCALE_PK 67108864.0f     // 2^26  (pick diffs <=40 -> <2^32 scaled)

typedef float f4 __attribute__((ext_vector_type(4)));

// ---------------------------------------------------------------------------
// One block per row, 256 threads. 1500 float4/row; threads 0..219 own 6
// float4s per array, the rest 5 (slot 5 clamped to a valid in-row address and
// its contribution skipped). All 12 loads are issued in ONE asm block with a
// single vmcnt(0) -> 12 loads guaranteed in flight per thread (compiler-level
// pinning failed twice: VGPR=36/32). Tail: fence-free integer-atomic reduce.
// ---------------------------------------------------------------------------
__global__ __launch_bounds__(256) void fused_loss(const float* __restrict__ pred,
                                                  const float* __restrict__ target,
                                                  unsigned long long* __restrict__ tot_l1,
                                                  unsigned long long* __restrict__ tot_pick,
                                                  unsigned int* __restrict__ counter,
                                                  float* __restrict__ out) {
    const int row  = blockIdx.x;
    const int tid  = threadIdx.x;
    const int wave = tid >> 6;
    const int lane = tid & 63;

    const uint64_t pb = (uint64_t)(pred   + (size_t)row * T_LEN);
    const uint64_t tb = (uint64_t)(target + (size_t)row * T_LEN);

    const bool has6 = (tid < (T_LEN / 4 - 5 * 256));   // tid < 220
    const uint32_t v0 = (uint32_t)tid * 16u;
    const uint32_t v1 = v0 + 1u * 4096u;
    const uint32_t v2 = v0 + 2u * 4096u;
    const uint32_t v3 = v0 + 3u * 4096u;
    const uint32_t v4 = v0 + 4u * 4096u;
    const uint32_t v5 = has6 ? (v0 + 5u * 4096u) : (uint32_t)((T_LEN / 4 - 1) * 16);

    f4 p0, p1, p2, p3, p4, p5, t0, t1, t2, t3, t4, t5;
    asm volatile(
        "global_load_dwordx4 %0,  %12, %18\n\t"
        "global_load_dwordx4 %1,  %13, %18\n\t"
        "global_load_dwordx4 %2,  %14, %18\n\t"
        "global_load_dwordx4 %3,  %15, %18\n\t"
        "global_load_dwordx4 %4,  %16, %18\n\t"
        "global_load_dwordx4 %5,  %17, %18\n\t"
        "global_load_dwordx4 %6,  %12, %19\n\t"
        "global_load_dwordx4 %7,  %13, %19\n\t"
        "global_load_dwordx4 %8,  %14, %19\n\t"
        "global_load_dwordx4 %9,  %15, %19\n\t"
        "global_load_dwordx4 %10, %16, %19\n\t"
        "global_load_dwordx4 %11, %17, %19\n\t"
        "s_waitcnt vmcnt(0)"
        : "=&v"(p0), "=&v"(p1), "=&v"(p2), "=&v"(p3), "=&v"(p4), "=&v"(p5),
          "=&v"(t0), "=&v"(t1), "=&v"(t2), "=&v"(t3), "=&v"(t4), "=&v"(t5)
        : "v"(v0), "v"(v1), "v"(v2), "v"(v3), "v"(v4), "v"(v5),
          "s"(pb), "s"(tb));
    __builtin_amdgcn_sched_barrier(0);

    float sum   = 0.0f;
    float bestv = -1.0f;            // |t| >= 0, always beaten
    int   besti = INT_MAX;

    // Indices strictly increase within a thread -> '>' keeps first occurrence.
#define CONSUME(PP, TT, K)                                                     \
    do {                                                                       \
        const int base = (tid + (K) * 256) * 4;                                \
        sum += fabsf(PP.x - TT.x) + fabsf(PP.y - TT.y) +                       \
               fabsf(PP.z - TT.z) + fabsf(PP.w - TT.w);                        \
        float a_;                                                              \
        a_ = fabsf(TT.x); if (a_ > bestv) { bestv = a_; besti = base;     }    \
        a_ = fabsf(TT.y); if (a_ > bestv) { bestv = a_; besti = base + 1; }    \
        a_ = fabsf(TT.z); if (a_ > bestv) { bestv = a_; besti = base + 2; }    \
        a_ = fabsf(TT.w); if (a_ > bestv) { bestv = a_; besti = base + 3; }    \
    } while (0)

    CONSUME(p0, t0, 0);
    CONSUME(p1, t1, 1);
    CONSUME(p2, t2, 2);
    CONSUME(p3, t3, 3);
    CONSUME(p4, t4, 4);
    if (has6) CONSUME(p5, t5, 5);
#undef CONSUME

    // ---- wave-level reduce: sum + argmax with tie -> min index
    #pragma unroll
    for (int o = 32; o > 0; o >>= 1) {
        sum += __shfl_xor(sum, o);
        const float ov = __shfl_xor(bestv, o);
        const int   oi = __shfl_xor(besti, o);
        if (ov > bestv || (ov == bestv && oi < besti)) { bestv = ov; besti = oi; }
    }

    __shared__ float s_sum[4];
    __shared__ float s_val[4];
    __shared__ int   s_idx[4];
    if (lane == 0) { s_sum[wave] = sum; s_val[wave] = bestv; s_idx[wave] = besti; }
    __syncthreads();

    // ---- wave 0: combine 4 partials, then the <=40-wide soft-argmax pick
    if (tid < 64) {
        float bs = 0.0f, bv = -1.0f;
        int   bi = INT_MAX;
        #pragma unroll
        for (int w = 0; w < 4; ++w) {
            bs += s_sum[w];
            if (s_val[w] > bv || (s_val[w] == bv && s_idx[w] < bi)) {
                bv = s_val[w]; bi = s_idx[w];
            }
        }

        const int c   = bi;
        const int s   = max(0, c - PICK_WIN);
        const int e   = min(T_LEN, c + PICK_WIN);
        const int len = e - s;

        float ap = -INFINITY, at = -INFINITY;
        const float posf = (float)(s + tid);
        if (tid < len) {
            const size_t idx = (size_t)row * T_LEN + s + tid;
            ap = BETA * fabsf(pred[idx]);     // L1/L2-hot: just streamed
            at = BETA * fabsf(target[idx]);
        }

        float mp = ap, mt = at;
        #pragma unroll
        for (int o = 32; o > 0; o >>= 1) {
            mp = fmaxf(mp, __shfl_xor(mp, o));
            mt = fmaxf(mt, __shfl_xor(mt, o));
        }

        float wp = 0.0f, wt = 0.0f, wpp = 0.0f, wtp = 0.0f;
        if (tid < len) {
            wp  = expf(ap - mp);
            wt  = expf(at - mt);
            wpp = wp * posf;
            wtp = wt * posf;
        }
        #pragma unroll
        for (int o = 32; o > 0; o >>= 1) {
            wp  += __shfl_xor(wp,  o);
            wt  += __shfl_xor(wt,  o);
            wpp += __shfl_xor(wpp, o);
            wtp += __shfl_xor(wtp, o);
        }

        if (tid == 0) {
            const float pickv = fabsf(wpp / wp - wtp / wt);

            // Fixed-point integer accumulation: associative -> deterministic,
            // and device-scope atomics need no cache fence (unlike round 3's
            // __threadfence, which invalidated L2 4096x and cost 4x).
            const unsigned long long i1 =
                (unsigned long long)llrintf(bs * SCALE_L1);
            const unsigned long long i2 =
                (unsigned long long)llrintf(pickv * SCALE_PK);
            unsigned long long r1 = atomicAdd(tot_l1, i1);
            unsigned long long r2 = atomicAdd(tot_pick, i2);
            // Using the returned values forces s_waitcnt vmcnt on them ->
            // both adds are globally visible before the counter bump below.
            asm volatile("" :: "v"(r1), "v"(r2) : "memory");

            const unsigned prev = atomicAdd(counter, 1u);
            if (prev == (unsigned)(B_ROWS - 1)) {
                // All 4096 value-adds are visible; read coherently via RMW.
                const unsigned long long s1 = atomicAdd(tot_l1, 0ull);
                const unsigned long long s2 = atomicAdd(tot_pick, 0ull);
                const double loss = ((double)s1 / (double)SCALE_L1) /
                                    ((double)B_ROWS * (double)T_LEN);
                const double pick = (((double)s2 / (double)SCALE_PK) /
                                     (double)B_ROWS) / (double)T_LEN;
                out[0] = (float)(loss + 0.1 * pick);
            }
        }
    }
}

extern "C" void kernel_launch(void* const* d_in, const int* in_sizes, int n_in,
                              void* d_out, int out_size, void* d_ws, size_t ws_size,
                              hipStream_t stream) {
    const float* pred   = (const float*)d_in[0];
    const float* target = (const float*)d_in[1];
    float* out = (float*)d_out;

    // workspace: [tot_l1: u64][tot_pick: u64][counter: u32]
    unsigned long long* tot_l1   = (unsigned long long*)d_ws;
    unsigned long long* tot_pick = tot_l1 + 1;
    unsigned int*       counter  = (unsigned int*)(tot_pick + 1);

    hipMemsetAsync(d_ws, 0, 24, stream);   // graph-capturable memset node
    fused_loss<<<B_ROWS, 256, 0, stream>>>(pred, target, tot_l1, tot_pick,
                                           counter, out);
}

// Round 5
// 40.421 us; speedup vs baseline: 4.1946x; 4.1363x over previous
//
#include <hip/hip_runtime.h>
#include <math.h>
#include <limits.h>
#include <stdint.h>

#define T_LEN 6000
#define B_ROWS 4096
#define PICK_WIN 20
#define BETA 25.0f

typedef float f4 __attribute__((ext_vector_type(4)));

// ---------------------------------------------------------------------------
// K1: per-row L1 sum + first-index argmax(|target|) + fused windowed
// soft-argmax pick. One block per row, 256 threads. 1500 float4/row:
// threads 0..219 own 6 float4s per array, the rest 5 (slot 5's address is
// clamped in-row; its contribution skipped). All 12 loads issued in ONE asm
// block with a single vmcnt(0) -> guaranteed 12-deep MLP per thread.
// NO global atomics (rounds 3/4 lesson: 4096 same-line RMWs serialize at the
// coherence point, ~90-200us of critical path; the tiny finalize kernel is
// ~3us). Tail reduce: wave shuffles + one barrier.
// ---------------------------------------------------------------------------
__global__ __launch_bounds__(256) void row_pass1(const float* __restrict__ pred,
                                                 const float* __restrict__ target,
                                                 float* __restrict__ row_l1,
                                                 float* __restrict__ row_pick) {
    const int row  = blockIdx.x;
    const int tid  = threadIdx.x;
    const int wave = tid >> 6;
    const int lane = tid & 63;

    const uint64_t pb = (uint64_t)(pred   + (size_t)row * T_LEN);
    const uint64_t tb = (uint64_t)(target + (size_t)row * T_LEN);

    const bool has6 = (tid < (T_LEN / 4 - 5 * 256));   // tid < 220
    const uint32_t v0 = (uint32_t)tid * 16u;
    const uint32_t v1 = v0 + 1u * 4096u;
    const uint32_t v2 = v0 + 2u * 4096u;
    const uint32_t v3 = v0 + 3u * 4096u;
    const uint32_t v4 = v0 + 4u * 4096u;
    const uint32_t v5 = has6 ? (v0 + 5u * 4096u) : (uint32_t)((T_LEN / 4 - 1) * 16);

    f4 p0, p1, p2, p3, p4, p5, t0, t1, t2, t3, t4, t5;
    asm volatile(
        "global_load_dwordx4 %0,  %12, %18\n\t"
        "global_load_dwordx4 %1,  %13, %18\n\t"
        "global_load_dwordx4 %2,  %14, %18\n\t"
        "global_load_dwordx4 %3,  %15, %18\n\t"
        "global_load_dwordx4 %4,  %16, %18\n\t"
        "global_load_dwordx4 %5,  %17, %18\n\t"
        "global_load_dwordx4 %6,  %12, %19\n\t"
        "global_load_dwordx4 %7,  %13, %19\n\t"
        "global_load_dwordx4 %8,  %14, %19\n\t"
        "global_load_dwordx4 %9,  %15, %19\n\t"
        "global_load_dwordx4 %10, %16, %19\n\t"
        "global_load_dwordx4 %11, %17, %19\n\t"
        "s_waitcnt vmcnt(0)"
        : "=&v"(p0), "=&v"(p1), "=&v"(p2), "=&v"(p3), "=&v"(p4), "=&v"(p5),
          "=&v"(t0), "=&v"(t1), "=&v"(t2), "=&v"(t3), "=&v"(t4), "=&v"(t5)
        : "v"(v0), "v"(v1), "v"(v2), "v"(v3), "v"(v4), "v"(v5),
          "s"(pb), "s"(tb));
    __builtin_amdgcn_sched_barrier(0);

    float sum   = 0.0f;
    float bestv = -1.0f;            // |t| >= 0, always beaten
    int   besti = INT_MAX;

    // Indices strictly increase within a thread -> '>' keeps first occurrence.
#define CONSUME(PP, TT, K)                                                     \
    do {                                                                       \
        const int base = (tid + (K) * 256) * 4;                                \
        sum += fabsf(PP.x - TT.x) + fabsf(PP.y - TT.y) +                       \
               fabsf(PP.z - TT.z) + fabsf(PP.w - TT.w);                        \
        float a_;                                                              \
        a_ = fabsf(TT.x); if (a_ > bestv) { bestv = a_; besti = base;     }    \
        a_ = fabsf(TT.y); if (a_ > bestv) { bestv = a_; besti = base + 1; }    \
        a_ = fabsf(TT.z); if (a_ > bestv) { bestv = a_; besti = base + 2; }    \
        a_ = fabsf(TT.w); if (a_ > bestv) { bestv = a_; besti = base + 3; }    \
    } while (0)

    CONSUME(p0, t0, 0);
    CONSUME(p1, t1, 1);
    CONSUME(p2, t2, 2);
    CONSUME(p3, t3, 3);
    CONSUME(p4, t4, 4);
    if (has6) CONSUME(p5, t5, 5);
#undef CONSUME

    // ---- wave-level reduce: sum + argmax with tie -> min index
    #pragma unroll
    for (int o = 32; o > 0; o >>= 1) {
        sum += __shfl_xor(sum, o);
        const float ov = __shfl_xor(bestv, o);
        const int   oi = __shfl_xor(besti, o);
        if (ov > bestv || (ov == bestv && oi < besti)) { bestv = ov; besti = oi; }
    }

    __shared__ float s_sum[4];
    __shared__ float s_val[4];
    __shared__ int   s_idx[4];
    if (lane == 0) { s_sum[wave] = sum; s_val[wave] = bestv; s_idx[wave] = besti; }
    __syncthreads();

    // ---- wave 0: combine 4 partials, then the <=40-wide soft-argmax pick
    if (tid < 64) {
        float bs = 0.0f, bv = -1.0f;
        int   bi = INT_MAX;
        #pragma unroll
        for (int w = 0; w < 4; ++w) {
            bs += s_sum[w];
            if (s_val[w] > bv || (s_val[w] == bv && s_idx[w] < bi)) {
                bv = s_val[w]; bi = s_idx[w];
            }
        }

        const int c   = bi;
        const int s   = max(0, c - PICK_WIN);
        const int e   = min(T_LEN, c + PICK_WIN);
        const int len = e - s;

        float ap = -INFINITY, at = -INFINITY;
        const float posf = (float)(s + tid);
        if (tid < len) {
            const size_t idx = (size_t)row * T_LEN + s + tid;
            ap = BETA * fabsf(pred[idx]);     // L1/L2-hot: just streamed
            at = BETA * fabsf(target[idx]);
        }

        float mp = ap, mt = at;
        #pragma unroll
        for (int o = 32; o > 0; o >>= 1) {
            mp = fmaxf(mp, __shfl_xor(mp, o));
            mt = fmaxf(mt, __shfl_xor(mt, o));
        }

        float wp = 0.0f, wt = 0.0f, wpp = 0.0f, wtp = 0.0f;
        if (tid < len) {
            wp  = expf(ap - mp);
            wt  = expf(at - mt);
            wpp = wp * posf;
            wtp = wt * posf;
        }
        #pragma unroll
        for (int o = 32; o > 0; o >>= 1) {
            wp  += __shfl_xor(wp,  o);
            wt  += __shfl_xor(wt,  o);
            wpp += __shfl_xor(wpp, o);
            wtp += __shfl_xor(wtp, o);
        }

        if (tid == 0) {
            row_l1[row]   = bs;
            row_pick[row] = fabsf(wpp / wp - wtp / wt);
        }
    }
}

// ---------------------------------------------------------------------------
// K2: deterministic final reduce + combine (1 block, ~3us — far cheaper than
// 4096 contended same-line atomics, per rounds 3/4).
// ---------------------------------------------------------------------------
__global__ __launch_bounds__(256) void finalize(const float* __restrict__ row_l1,
                                                const float* __restrict__ row_pick,
                                                float* __restrict__ out) {
    const int tid  = threadIdx.x;
    const int wave = tid >> 6;
    const int lane = tid & 63;
    float a = 0.0f, b = 0.0f;
    for (int i = tid; i < B_ROWS; i += 256) {
        a += row_l1[i];
        b += row_pick[i];
    }
    #pragma unroll
    for (int o = 32; o > 0; o >>= 1) {
        a += __shfl_xor(a, o);
        b += __shfl_xor(b, o);
    }
    __shared__ float f1[4], f2[4];
    if (lane == 0) { f1[wave] = a; f2[wave] = b; }
    __syncthreads();
    if (tid == 0) {
        const float ta = f1[0] + f1[1] + f1[2] + f1[3];
        const float tb = f2[0] + f2[1] + f2[2] + f2[3];
        const float loss = ta / (float)((long long)B_ROWS * (long long)T_LEN);
        const float pick = (tb / (float)B_ROWS) / (float)T_LEN;
        out[0] = loss + 0.1f * pick;
    }
}

extern "C" void kernel_launch(void* const* d_in, const int* in_sizes, int n_in,
                              void* d_out, int out_size, void* d_ws, size_t ws_size,
                              hipStream_t stream) {
    const float* pred   = (const float*)d_in[0];
    const float* target = (const float*)d_in[1];
    float* out = (float*)d_out;

    // workspace layout: [row_l1: 4096 f32][row_pick: 4096 f32]
    float* row_l1   = (float*)d_ws;
    float* row_pick = row_l1 + B_ROWS;

    row_pass1<<<B_ROWS, 256, 0, stream>>>(pred, target, row_l1, row_pick);
    finalize<<<1, 256, 0, stream>>>(row_l1, row_pick, out);
}

// Round 6
// 37.684 us; speedup vs baseline: 4.4993x; 1.0726x over previous
//
#include <hip/hip_runtime.h>
#include <math.h>
#include <limits.h>
#include <stdint.h>

#define T_LEN 6000
#define B_ROWS 4096
#define PICK_WIN 20
#define BETA 25.0f

typedef float f4 __attribute__((ext_vector_type(4)));

// ---------------------------------------------------------------------------
// K1: 2 rows per block (grid 2048). Per row: L1 sum + first-index
// argmax(|target|) + fused windowed soft-argmax pick.
// Loads: both rows' 12 dwordx4 clusters issued back-to-back (24 in flight);
// row0 consumed at vmcnt(12) while row1's loads still fly; row1 at vmcnt(0).
// Tail: interleaved wave reduce for both rows, one barrier, wave0 does row0's
// pick while wave1 does row1's (concurrent). No global atomics (r3/r4: same-
// line RMWs serialize ~20-40cy each at the coherence point).
// ---------------------------------------------------------------------------
__global__ __launch_bounds__(256) void row_pass1(const float* __restrict__ pred,
                                                 const float* __restrict__ target,
                                                 float* __restrict__ row_l1,
                                                 float* __restrict__ row_pick) {
    const int row0 = blockIdx.x * 2;
    const int row1 = row0 + 1;
    const int tid  = threadIdx.x;
    const int wave = tid >> 6;
    const int lane = tid & 63;

    const uint64_t pb0 = (uint64_t)(pred   + (size_t)row0 * T_LEN);
    const uint64_t tb0 = (uint64_t)(target + (size_t)row0 * T_LEN);
    const uint64_t pb1 = (uint64_t)(pred   + (size_t)row1 * T_LEN);
    const uint64_t tb1 = (uint64_t)(target + (size_t)row1 * T_LEN);

    const bool has6 = (tid < (T_LEN / 4 - 5 * 256));   // tid < 220
    const uint32_t v0 = (uint32_t)tid * 16u;
    const uint32_t v1 = v0 + 1u * 4096u;
    const uint32_t v2 = v0 + 2u * 4096u;
    const uint32_t v3 = v0 + 3u * 4096u;
    const uint32_t v4 = v0 + 4u * 4096u;
    const uint32_t v5 = has6 ? (v0 + 5u * 4096u) : (uint32_t)((T_LEN / 4 - 1) * 16);

    f4 a0, a1, a2, a3, a4, a5, b0, b1, b2, b3, b4, b5;   // row0 pred/target
    f4 c0, c1, c2, c3, c4, c5, d0, d1, d2, d3, d4, d5;   // row1 pred/target
    asm volatile(
        "global_load_dwordx4 %0,  %12, %18\n\t"
        "global_load_dwordx4 %1,  %13, %18\n\t"
        "global_load_dwordx4 %2,  %14, %18\n\t"
        "global_load_dwordx4 %3,  %15, %18\n\t"
        "global_load_dwordx4 %4,  %16, %18\n\t"
        "global_load_dwordx4 %5,  %17, %18\n\t"
        "global_load_dwordx4 %6,  %12, %19\n\t"
        "global_load_dwordx4 %7,  %13, %19\n\t"
        "global_load_dwordx4 %8,  %14, %19\n\t"
        "global_load_dwordx4 %9,  %15, %19\n\t"
        "global_load_dwordx4 %10, %16, %19\n\t"
        "global_load_dwordx4 %11, %17, %19"
        : "=&v"(a0), "=&v"(a1), "=&v"(a2), "=&v"(a3), "=&v"(a4), "=&v"(a5),
          "=&v"(b0), "=&v"(b1), "=&v"(b2), "=&v"(b3), "=&v"(b4), "=&v"(b5)
        : "v"(v0), "v"(v1), "v"(v2), "v"(v3), "v"(v4), "v"(v5),
          "s"(pb0), "s"(tb0));
    asm volatile(
        "global_load_dwordx4 %0,  %12, %18\n\t"
        "global_load_dwordx4 %1,  %13, %18\n\t"
        "global_load_dwordx4 %2,  %14, %18\n\t"
        "global_load_dwordx4 %3,  %15, %18\n\t"
        "global_load_dwordx4 %4,  %16, %18\n\t"
        "global_load_dwordx4 %5,  %17, %18\n\t"
        "global_load_dwordx4 %6,  %12, %19\n\t"
        "global_load_dwordx4 %7,  %13, %19\n\t"
        "global_load_dwordx4 %8,  %14, %19\n\t"
        "global_load_dwordx4 %9,  %15, %19\n\t"
        "global_load_dwordx4 %10, %16, %19\n\t"
        "global_load_dwordx4 %11, %17, %19"
        : "=&v"(c0), "=&v"(c1), "=&v"(c2), "=&v"(c3), "=&v"(c4), "=&v"(c5),
          "=&v"(d0), "=&v"(d1), "=&v"(d2), "=&v"(d3), "=&v"(d4), "=&v"(d5)
        : "v"(v0), "v"(v1), "v"(v2), "v"(v3), "v"(v4), "v"(v5),
          "s"(pb1), "s"(tb1));

    float sum0 = 0.0f, sum1 = 0.0f;
    float bv0 = -1.0f, bv1 = -1.0f;      // |t| >= 0, always beaten
    int   bi0 = INT_MAX, bi1 = INT_MAX;

    // Indices strictly increase within a thread -> '>' keeps first occurrence.
#define CONSUME(PP, TT, K, SUM, BV, BI)                                        \
    do {                                                                       \
        const int base = (tid + (K) * 256) * 4;                                \
        SUM += fabsf(PP.x - TT.x) + fabsf(PP.y - TT.y) +                       \
               fabsf(PP.z - TT.z) + fabsf(PP.w - TT.w);                        \
        float a_;                                                              \
        a_ = fabsf(TT.x); if (a_ > BV) { BV = a_; BI = base;     }             \
        a_ = fabsf(TT.y); if (a_ > BV) { BV = a_; BI = base + 1; }             \
        a_ = fabsf(TT.z); if (a_ > BV) { BV = a_; BI = base + 2; }             \
        a_ = fabsf(TT.w); if (a_ > BV) { BV = a_; BI = base + 3; }             \
    } while (0)

    // row0 consume: row1's 12 loads may remain outstanding
    asm volatile("s_waitcnt vmcnt(12)" ::: "memory");
    __builtin_amdgcn_sched_barrier(0);
    CONSUME(a0, b0, 0, sum0, bv0, bi0);
    CONSUME(a1, b1, 1, sum0, bv0, bi0);
    CONSUME(a2, b2, 2, sum0, bv0, bi0);
    CONSUME(a3, b3, 3, sum0, bv0, bi0);
    CONSUME(a4, b4, 4, sum0, bv0, bi0);
    if (has6) CONSUME(a5, b5, 5, sum0, bv0, bi0);

    asm volatile("s_waitcnt vmcnt(0)" ::: "memory");
    __builtin_amdgcn_sched_barrier(0);
    CONSUME(c0, d0, 0, sum1, bv1, bi1);
    CONSUME(c1, d1, 1, sum1, bv1, bi1);
    CONSUME(c2, d2, 2, sum1, bv1, bi1);
    CONSUME(c3, d3, 3, sum1, bv1, bi1);
    CONSUME(c4, d4, 4, sum1, bv1, bi1);
    if (has6) CONSUME(c5, d5, 5, sum1, bv1, bi1);
#undef CONSUME

    // ---- interleaved wave reduce (both rows): sum + argmax (tie -> min idx)
    #pragma unroll
    for (int o = 32; o > 0; o >>= 1) {
        sum0 += __shfl_xor(sum0, o);
        sum1 += __shfl_xor(sum1, o);
        const float ov0 = __shfl_xor(bv0, o);
        const int   oi0 = __shfl_xor(bi0, o);
        const float ov1 = __shfl_xor(bv1, o);
        const int   oi1 = __shfl_xor(bi1, o);
        if (ov0 > bv0 || (ov0 == bv0 && oi0 < bi0)) { bv0 = ov0; bi0 = oi0; }
        if (ov1 > bv1 || (ov1 == bv1 && oi1 < bi1)) { bv1 = ov1; bi1 = oi1; }
    }

    __shared__ float s_sum[2][4];
    __shared__ float s_val[2][4];
    __shared__ int   s_idx[2][4];
    if (lane == 0) {
        s_sum[0][wave] = sum0; s_val[0][wave] = bv0; s_idx[0][wave] = bi0;
        s_sum[1][wave] = sum1; s_val[1][wave] = bv1; s_idx[1][wave] = bi1;
    }
    __syncthreads();

    // ---- wave 0 -> row0 pick, wave 1 -> row1 pick (concurrent)
    if (wave < 2) {
        const int r = wave;
        const int row = row0 + r;
        float bs = 0.0f, bv = -1.0f;
        int   bi = INT_MAX;
        #pragma unroll
        for (int w = 0; w < 4; ++w) {
            bs += s_sum[r][w];
            if (s_val[r][w] > bv || (s_val[r][w] == bv && s_idx[r][w] < bi)) {
                bv = s_val[r][w]; bi = s_idx[r][w];
            }
        }

        const int c   = bi;
        const int s   = max(0, c - PICK_WIN);
        const int e   = min(T_LEN, c + PICK_WIN);
        const int len = e - s;

        float ap = -INFINITY, at = -INFINITY;
        const float posf = (float)(s + lane);
        if (lane < len) {
            const size_t idx = (size_t)row * T_LEN + s + lane;
            ap = BETA * fabsf(pred[idx]);     // L2-hot: just streamed
            at = BETA * fabsf(target[idx]);
        }

        float mp = ap, mt = at;
        #pragma unroll
        for (int o = 32; o > 0; o >>= 1) {
            mp = fmaxf(mp, __shfl_xor(mp, o));
            mt = fmaxf(mt, __shfl_xor(mt, o));
        }

        float wp = 0.0f, wt = 0.0f, wpp = 0.0f, wtp = 0.0f;
        if (lane < len) {
            wp  = expf(ap - mp);
            wt  = expf(at - mt);
            wpp = wp * posf;
            wtp = wt * posf;
        }
        #pragma unroll
        for (int o = 32; o > 0; o >>= 1) {
            wp  += __shfl_xor(wp,  o);
            wt  += __shfl_xor(wt,  o);
            wpp += __shfl_xor(wpp, o);
            wtp += __shfl_xor(wtp, o);
        }

        if (lane == 0) {
            row_l1[row]   = bs;
            row_pick[row] = fabsf(wpp / wp - wtp / wt);
        }
    }
}

// ---------------------------------------------------------------------------
// K2: deterministic final reduce + combine. float4 loads (both arrays are
// contiguous, 4096 f32 each -> 4 f4/thread/array).
// ---------------------------------------------------------------------------
__global__ __launch_bounds__(256) void finalize(const float* __restrict__ row_l1,
                                                const float* __restrict__ row_pick,
                                                float* __restrict__ out) {
    const int tid  = threadIdx.x;
    const int wave = tid >> 6;
    const int lane = tid & 63;
    const f4* l4 = (const f4*)row_l1;
    const f4* p4 = (const f4*)row_pick;

    float a = 0.0f, b = 0.0f;
    #pragma unroll
    for (int k = 0; k < 4; ++k) {
        const f4 x = l4[tid + k * 256];
        const f4 y = p4[tid + k * 256];
        a += x.x + x.y + x.z + x.w;
        b += y.x + y.y + y.z + y.w;
    }
    #pragma unroll
    for (int o = 32; o > 0; o >>= 1) {
        a += __shfl_xor(a, o);
        b += __shfl_xor(b, o);
    }
    __shared__ float f1[4], f2[4];
    if (lane == 0) { f1[wave] = a; f2[wave] = b; }
    __syncthreads();
    if (tid == 0) {
        const float ta = f1[0] + f1[1] + f1[2] + f1[3];
        const float tb = f2[0] + f2[1] + f2[2] + f2[3];
        const float loss = ta / (float)((long long)B_ROWS * (long long)T_LEN);
        const float pick = (tb / (float)B_ROWS) / (float)T_LEN;
        out[0] = loss + 0.1f * pick;
    }
}

extern "C" void kernel_launch(void* const* d_in, const int* in_sizes, int n_in,
                              void* d_out, int out_size, void* d_ws, size_t ws_size,
                              hipStream_t stream) {
    const float* pred   = (const float*)d_in[0];
    const float* target = (const float*)d_in[1];
    float* out = (float*)d_out;

    // workspace layout: [row_l1: 4096 f32][row_pick: 4096 f32]
    float* row_l1   = (float*)d_ws;
    float* row_pick = row_l1 + B_ROWS;

    row_pass1<<<B_ROWS / 2, 256, 0, stream>>>(pred, target, row_l1, row_pick);
    finalize<<<1, 256, 0, stream>>>(row_l1, row_pick, out);
}